// Round 12
// baseline (666.524 us; speedup 1.0000x reference)
//
#include <hip/hip_runtime.h>

// VQ nearest-neighbor: argmin_k ||c_k||^2 - 2 x_n . c_k
// N=32768 rows, K=8192 codes, D=512, fp32 in, int32 indices out.
//
// Round 12: single-barrier step. r6->r11 step-time analysis shows ~4800
// cyc/step of structural overhead (2 barriers + phase-serial read/MFMA).
// Changes: (1) X fragments come straight from global via a transposed
// tile layout XT[rowTile64][octet][rowIn64] (coalesced 2x512B per b128
// fragment) with register prefetch one step ahead -- X is fully decoupled
// from the barrier pipeline; (2) C is triple-buffered in LDS (3x16KB),
// STAGE issued AFTER the barrier (depth-2 prefetch, vmcnt(6) counted) ->
// exactly ONE s_barrier per K-step. Buffer written at step s was read at
// step s-1 and the step-s barrier separates them (waves pass it only
// after their MFMA operand waits drain their cv reads). fp16 math +
// top-3 + exact-refine tail unchanged from r11.

#define D_DIM 512
#define EPS_GAP 0.082f     // scaled (4096x) units = 2e-5 unscaled
#define KSPLIT 8

typedef __attribute__((ext_vector_type(16))) float f32x16;
typedef _Float16 half8v __attribute__((ext_vector_type(8)));
typedef _Float16 half4v __attribute__((ext_vector_type(4)));

__device__ __forceinline__ void gload_lds16(const void* g, void* l) {
    __builtin_amdgcn_global_load_lds(
        (const __attribute__((address_space(1))) unsigned int*)g,
        (__attribute__((address_space(3))) unsigned int*)l, 16, 0, 0);
}

__device__ __forceinline__ void ins3(float d, int i, float& d1, int& i1,
                                     float& d2, int& i2, float& d3) {
    if (d < d1 || (d == d1 && i < i1)) { d3 = d2; d2 = d1; i2 = i1; d1 = d; i1 = i; }
    else if (d < d2 || (d == d2 && i < i2)) { d3 = d2; d2 = d; i2 = i; }
    else if (d < d3) d3 = d;
}

// ---- pass 0: CB -> fp16(x4096) + ||c||^2; X -> XT transposed fp16 tiles ----
// XT layout (16B half8v units): tile = row/64; idx = tile*4096 + octet*64
// + (row%64), octet = k/8 (64 octets over D=512).
__global__ __launch_bounds__(256) void prep_kernel(
        const float* __restrict__ X, const float* __restrict__ CB,
        _Float16* __restrict__ XT, _Float16* __restrict__ Ch,
        float* __restrict__ cbs, int* __restrict__ cnt,
        int K, int cbBlocks) {
    const int bid = blockIdx.x;
    const int tid = threadIdx.x;
    if (bid == 0 && tid == 0) *cnt = 0;
    if (bid < cbBlocks) {
        int w = bid * 4 + (tid >> 6);
        int lane = tid & 63;
        if (w >= K) return;
        size_t base = (size_t)w * D_DIM + lane * 8;
        const float4* r4 = (const float4*)(CB + base);
        float4 u = r4[0], v = r4[1];
        float s = u.x*u.x + u.y*u.y + u.z*u.z + u.w*u.w
                + v.x*v.x + v.y*v.y + v.z*v.z + v.w*v.w;
        half8v h;
        h[0] = (_Float16)(u.x * 4096.f); h[1] = (_Float16)(u.y * 4096.f);
        h[2] = (_Float16)(u.z * 4096.f); h[3] = (_Float16)(u.w * 4096.f);
        h[4] = (_Float16)(v.x * 4096.f); h[5] = (_Float16)(v.y * 4096.f);
        h[6] = (_Float16)(v.z * 4096.f); h[7] = (_Float16)(v.w * 4096.f);
        *(half8v*)(Ch + base) = h;
#pragma unroll
        for (int off = 32; off; off >>= 1) s += __shfl_xor(s, off);
        if (lane == 0) cbs[w] = s;
    } else {
        // X transpose: block handles one 64-row tile.
        const int tile = bid - cbBlocks;
        const int o  = tid & 63;        // octet (coalesced read dim)
        const int rq = tid >> 6;        // 0..3
        half8v* XT8 = (half8v*)XT;
#pragma unroll 4
        for (int rr = 0; rr < 16; ++rr) {
            int r = rq * 16 + rr;
            size_t src = (size_t)(tile * 64 + r) * D_DIM + o * 8;
            float4 a = *(const float4*)&X[src];
            float4 b = *(const float4*)&X[src + 4];
            half8v h;
            h[0] = (_Float16)a.x; h[1] = (_Float16)a.y;
            h[2] = (_Float16)a.z; h[3] = (_Float16)a.w;
            h[4] = (_Float16)b.x; h[5] = (_Float16)b.y;
            h[6] = (_Float16)b.z; h[7] = (_Float16)b.w;
            XT8[tile * 4096 + o * 64 + r] = h;
        }
    }
}

// ---- pass 1: transposed fp16 MFMA dists + per-lane top-3, 1 barrier/step ----
__global__ __launch_bounds__(512, 2) void vq_mfma_kernel(
        const _Float16* __restrict__ XT, const _Float16* __restrict__ Ch,
        const float* __restrict__ cbs,
        float* __restrict__ pd1, int* __restrict__ pi1,
        float* __restrict__ pd2, int* __restrict__ pi2,
        float* __restrict__ pd3, int N, int K) {

    __shared__ _Float16 Cs[3][256 * 32];   // 16KB per buffer

    const int tid  = threadIdx.x;
    const int lane = tid & 63;
    const int w    = tid >> 6;
    const int wr   = w >> 2;       // code half
    const int wcq  = w & 3;        // x quad
    const int bid  = blockIdx.x;
    const int split     = bid & (KSPLIT - 1);
    const int rowBase   = (bid >> 3) * 256;
    const int kPerSplit = K / KSPLIT;
    const int splitBase = split * kPerSplit;
    const int NT        = kPerSplit / 256;
    const int nSteps    = NT * 16;

    // C staging (verbatim r11 C-part): lane l -> rows w*32+(l>>2), +16.
    const int l4  = lane >> 2;
    const int swz = ((lane & 3) ^ ((lane >> 3) & 3)) * 8;
    const int sflip = (swz ^ 16) - swz;
    const size_t gC0 = (size_t)(w * 32 + l4) * D_DIM + swz;
    const int l0 = w * 1024 + lane * 8;

    // C fragment reads (verbatim r11)
    const int lh = lane >> 5;
    const int rC = wr * 128 + (lane & 31);
    const int kp = ((lane >> 1) & 3) ^ (((lane >> 4) & 1) << 1);
    const int kOff0 = (lh ^ kp) * 8;
    const int kOff1 = kOff0 ^ 16;

    // X fragment global address (half8v units)
    const half8v* XT8 = (const half8v*)XT;
    const int xb0 = ((rowBase >> 6) + wcq) * 4096 + lh * 64 + (lane & 31);

    float d1v[2], d2v[2], d3v[2];
    int   i1v[2], i2v[2];
#pragma unroll
    for (int nf = 0; nf < 2; ++nf) {
        d1v[nf] = 3.4e38f; d2v[nf] = 3.4e38f; d3v[nf] = 3.4e38f;
        i1v[nf] = 0x7fffffff; i2v[nf] = 0x7fffffff;
    }

    f32x16 acc[4][2];

    auto fold = [&](int ctF) {
        const int cb0 = splitBase + ctF * 256 + wr * 128 + 4 * lh;
#pragma unroll
        for (int mf = 0; mf < 4; ++mf)
#pragma unroll
            for (int rq = 0; rq < 4; ++rq) {
                float4 c2q = *(const float4*)&cbs[cb0 + mf * 32 + rq * 8];
#pragma unroll
                for (int j = 0; j < 4; ++j) {
                    const int code = cb0 + mf * 32 + rq * 8 + j;
                    const int reg  = rq * 4 + j;
                    const float c2 = (&c2q.x)[j] * 4096.f;
#pragma unroll
                    for (int nf = 0; nf < 2; ++nf) {
                        float dist = fmaf(-2.f, acc[mf][nf][reg], c2);
                        ins3(dist, code, d1v[nf], i1v[nf], d2v[nf], i2v[nf], d3v[nf]);
                    }
                }
            }
    };

#define STAGE(buf, s_)                                                        \
    do { int ct_ = (s_) >> 4, kt_ = (s_) & 15;                                \
        size_t cb_ = (size_t)(splitBase + ct_ * 256) * D_DIM + gC0 + kt_ * 32;\
        gload_lds16(Ch + cb_,                        &Cs[buf][l0]);           \
        gload_lds16(Ch + cb_ + 16 * D_DIM + sflip,   &Cs[buf][l0 + 512]);     \
    } while (0)

    // prologue: depth-2 C prefetch + step-0 X fragments
    STAGE(0, 0);
    STAGE(1, 1);
    half8v xvC[2][2], xvN[2][2];
#pragma unroll
    for (int nf = 0; nf < 2; ++nf)
#pragma unroll
        for (int kh = 0; kh < 2; ++kh)
            xvC[nf][kh] = XT8[xb0 + kh * 128 + nf * 32];   // kt=0

    int bufR = 0, bufW = 2;

    for (int s = 0; s < nSteps; ++s) {
        const int kt = s & 15;
        const int ct = s >> 4;

        if (s + 2 < nSteps) {
            // queue (oldest->newest) <= [S(s) 2, S(s+1) 2, X(s) 4] at s<2;
            // steady-state S(s) is already drained by the in-order wait for
            // X(s-1) before step s-1's MFMAs. vmcnt(6) covers both cases.
            asm volatile("s_waitcnt vmcnt(6)" ::: "memory");
        } else {
            asm volatile("s_waitcnt vmcnt(0)" ::: "memory");
        }
        __builtin_amdgcn_s_barrier();          // buf bufR staged, prev reads done
        __builtin_amdgcn_sched_barrier(0);     // nothing hoists above barrier

        if (s + 2 < nSteps) STAGE(bufW, s + 2);
        if (s + 1 < nSteps) {
            const int kt1 = (s + 1) & 15;
#pragma unroll
            for (int nf = 0; nf < 2; ++nf)
#pragma unroll
                for (int kh = 0; kh < 2; ++kh)
                    xvN[nf][kh] = XT8[xb0 + kt1 * 256 + kh * 128 + nf * 32];
        }

        half8v cv[4][2];
#pragma unroll
        for (int mf = 0; mf < 4; ++mf) {
            cv[mf][0] = *(const half8v*)&Cs[bufR][(rC + mf * 32) * 32 + kOff0];
            cv[mf][1] = *(const half8v*)&Cs[bufR][(rC + mf * 32) * 32 + kOff1];
        }

        if (kt == 0) {
            if (s) fold(ct - 1);
#pragma unroll
            for (int mf = 0; mf < 4; ++mf)
#pragma unroll
                for (int nf = 0; nf < 2; ++nf)
#pragma unroll
                    for (int r = 0; r < 16; ++r) acc[mf][nf][r] = 0.f;
        }

#pragma unroll
        for (int kh = 0; kh < 2; ++kh)
#pragma unroll
            for (int mf = 0; mf < 4; ++mf)
#pragma unroll
                for (int nf = 0; nf < 2; ++nf)
                    acc[mf][nf] = __builtin_amdgcn_mfma_f32_32x32x16_f16(
                        cv[mf][kh], xvC[nf][kh], acc[mf][nf], 0, 0, 0);

#pragma unroll
        for (int nf = 0; nf < 2; ++nf)
#pragma unroll
            for (int kh = 0; kh < 2; ++kh)
                xvC[nf][kh] = xvN[nf][kh];

        if (++bufR == 3) bufR = 0;
        if (++bufW == 3) bufW = 0;
    }
#undef STAGE

    fold(NT - 1);

    // merge lane halves (l <-> l^32)
#pragma unroll
    for (int nf = 0; nf < 2; ++nf) {
        float od1 = __shfl_xor(d1v[nf], 32);
        int   oi1 = __shfl_xor(i1v[nf], 32);
        float od2 = __shfl_xor(d2v[nf], 32);
        int   oi2 = __shfl_xor(i2v[nf], 32);
        float od3 = __shfl_xor(d3v[nf], 32);
        ins3(od1, oi1, d1v[nf], i1v[nf], d2v[nf], i2v[nf], d3v[nf]);
        ins3(od2, oi2, d1v[nf], i1v[nf], d2v[nf], i2v[nf], d3v[nf]);
        d3v[nf] = fminf(d3v[nf], od3);
    }

    // cross-wr merge via LDS overlay on Cs[0]
    __syncthreads();
    float* mD1 = (float*)&Cs[0][0];
    int*   mI1 = (int*)(mD1 + 256);
    float* mD2 = (float*)(mD1 + 512);
    int*   mI2 = (int*)(mD1 + 768);
    float* mD3 = (float*)(mD1 + 1024);
    if (wr == 1 && lane < 32) {
#pragma unroll
        for (int nf = 0; nf < 2; ++nf) {
            int x = wcq * 64 + nf * 32 + (lane & 31);
            mD1[x] = d1v[nf]; mI1[x] = i1v[nf];
            mD2[x] = d2v[nf]; mI2[x] = i2v[nf];
            mD3[x] = d3v[nf];
        }
    }
    __syncthreads();
    if (wr == 0 && lane < 32) {
#pragma unroll
        for (int nf = 0; nf < 2; ++nf) {
            int x = wcq * 64 + nf * 32 + (lane & 31);
            float d1 = d1v[nf], d2 = d2v[nf], d3 = d3v[nf];
            int i1 = i1v[nf], i2 = i2v[nf];
            ins3(mD1[x], mI1[x], d1, i1, d2, i2, d3);
            ins3(mD2[x], mI2[x], d1, i1, d2, i2, d3);
            d3 = fminf(d3, mD3[x]);
            size_t p = (size_t)split * N + (rowBase + x);
            pd1[p] = d1; pi1[p] = i1; pd2[p] = d2; pi2[p] = i2; pd3[p] = d3;
        }
    }
}

// ---- pass 2: merge splits; 2-way ties inline exact; 3-way -> flag list ----
__global__ __launch_bounds__(256) void combine_kernel(
        const float* __restrict__ X, const float* __restrict__ CB,
        const float* __restrict__ cbs,
        const float* __restrict__ pd1, const int* __restrict__ pi1,
        const float* __restrict__ pd2, const int* __restrict__ pi2,
        const float* __restrict__ pd3,
        int* __restrict__ out, int* __restrict__ flags, int* __restrict__ cnt,
        int N, int S) {
    const int row = blockIdx.x * 256 + threadIdx.x;
    if (row >= N) return;
    float d1 = pd1[row], d2 = pd2[row], d3 = pd3[row];
    int i1 = pi1[row], i2 = pi2[row];
    for (int s = 1; s < S; ++s) {
        size_t p = (size_t)s * N + row;
        ins3(pd1[p], pi1[p], d1, i1, d2, i2, d3);
        ins3(pd2[p], pi2[p], d1, i1, d2, i2, d3);
        d3 = fminf(d3, pd3[p]);
    }
    int best = i1;
    if (d2 - d1 < EPS_GAP) {
        if (d3 - d1 < EPS_GAP) {
            int f = atomicAdd(cnt, 1);
            flags[f] = row;
        } else {
            const float4* xr = (const float4*)(X + (size_t)row * D_DIM);
            const float4* ca = (const float4*)(CB + (size_t)i1 * D_DIM);
            const float4* cb = (const float4*)(CB + (size_t)i2 * D_DIM);
            float dotA = 0.f, dotB = 0.f;
#pragma unroll 4
            for (int d = 0; d < D_DIM / 4; ++d) {
                float4 xv = xr[d], av = ca[d], bv = cb[d];
                dotA = fmaf(xv.x, av.x, dotA); dotA = fmaf(xv.y, av.y, dotA);
                dotA = fmaf(xv.z, av.z, dotA); dotA = fmaf(xv.w, av.w, dotA);
                dotB = fmaf(xv.x, bv.x, dotB); dotB = fmaf(xv.y, bv.y, dotB);
                dotB = fmaf(xv.z, bv.z, dotB); dotB = fmaf(xv.w, bv.w, dotB);
            }
            float dA = fmaf(-2.f, dotA, cbs[i1]);
            float dB = fmaf(-2.f, dotB, cbs[i2]);
            best = (dB < dA || (dB == dA && i2 < i1)) ? i2 : i1;
        }
    }
    out[row] = best;
}

// ---- pass 3: parallel exact scan of flagged rows (row x 32 chunks) ----
__global__ __launch_bounds__(256) void rare_scan_kernel(
        const float* __restrict__ X, const float* __restrict__ CB,
        const float* __restrict__ cbs,
        const int* __restrict__ flags, const int* __restrict__ cnt,
        float* __restrict__ scrD, int* __restrict__ scrI, int K) {
    __shared__ float xs[D_DIM];
    __shared__ float rD[4];
    __shared__ int   rI[4];
    const int nTasks = (*cnt) * 32;
    const int cpc = K / 32;
    for (int t = blockIdx.x; t < nTasks; t += gridDim.x) {
        const int fi = t >> 5, chunk = t & 31;
        const int row = flags[fi];
        __syncthreads();
        for (int i = threadIdx.x; i < D_DIM; i += 256)
            xs[i] = X[(size_t)row * D_DIM + i];
        __syncthreads();
        float bd = 3.4e38f; int bi = 0x7fffffff;
        for (int c = chunk * cpc + threadIdx.x; c < (chunk + 1) * cpc; c += 256) {
            const float4* cp = (const float4*)(CB + (size_t)c * D_DIM);
            float dot = 0.f;
#pragma unroll 4
            for (int d = 0; d < D_DIM / 4; ++d) {
                float4 cv = cp[d];
                float4 xv = *(const float4*)&xs[d * 4];
                dot = fmaf(xv.x, cv.x, dot); dot = fmaf(xv.y, cv.y, dot);
                dot = fmaf(xv.z, cv.z, dot); dot = fmaf(xv.w, cv.w, dot);
            }
            float dist = fmaf(-2.f, dot, cbs[c]);
            if (dist < bd || (dist == bd && c < bi)) { bd = dist; bi = c; }
        }
#pragma unroll
        for (int off = 1; off < 64; off <<= 1) {
            float od = __shfl_xor(bd, off);
            int   oi = __shfl_xor(bi, off);
            if (od < bd || (od == bd && oi < bi)) { bd = od; bi = oi; }
        }
        if ((threadIdx.x & 63) == 0) { rD[threadIdx.x >> 6] = bd; rI[threadIdx.x >> 6] = bi; }
        __syncthreads();
        if (threadIdx.x == 0) {
            for (int ww = 1; ww < 4; ++ww)
                if (rD[ww] < bd || (rD[ww] == bd && rI[ww] < bi)) {
                    bd = rD[ww]; bi = rI[ww];
                }
            scrD[t] = bd; scrI[t] = bi;
        }
    }
}

// ---- pass 4: reduce 32 chunk partials per flagged row ----
__global__ __launch_bounds__(256) void rare_write_kernel(
        const int* __restrict__ flags, const int* __restrict__ cnt,
        const float* __restrict__ scrD, const int* __restrict__ scrI,
        int* __restrict__ out) {
    const int nf = *cnt;
    for (int fi = blockIdx.x * 256 + threadIdx.x; fi < nf;
         fi += gridDim.x * 256) {
        float bd = scrD[fi * 32]; int bi = scrI[fi * 32];
        for (int ch = 1; ch < 32; ++ch) {
            float d = scrD[fi * 32 + ch]; int i = scrI[fi * 32 + ch];
            if (d < bd || (d == bd && i < bi)) { bd = d; bi = i; }
        }
        out[flags[fi]] = bi;
    }
}

// ================= fp32 fallback (generic shapes) =================
#define BM 128
#define BN 128
#define BD 16

__global__ __launch_bounds__(256) void cbsqr_kernel(const float* __restrict__ cb,
                                                    float* __restrict__ out, int K) {
    int gtid = blockIdx.x * blockDim.x + threadIdx.x;
    int w = gtid >> 6;
    int lane = gtid & 63;
    if (w >= K) return;
    const float4* r4 = (const float4*)(cb + (size_t)w * D_DIM) + lane * 2;
    float4 u = r4[0], v = r4[1];
    float s = u.x*u.x + u.y*u.y + u.z*u.z + u.w*u.w
            + v.x*v.x + v.y*v.y + v.z*v.z + v.w*v.w;
#pragma unroll
    for (int off = 32; off; off >>= 1) s += __shfl_xor(s, off);
    if (lane == 0) out[w] = s;
}

__global__ __launch_bounds__(128) void vq_fp32_kernel(
        const float* __restrict__ X, const float* __restrict__ CB,
        const float* __restrict__ cbs,
        float* __restrict__ pd, int* __restrict__ pi,
        int* __restrict__ out, int N, int K, int nsplit) {

    __shared__ float As[BD][BM + 4];
    __shared__ float Bs[BD][BN + 4];

    const int tid = threadIdx.x;
    const int tx = tid & 7;
    const int ty = tid >> 3;
    const int rowBase = blockIdx.x * BM;
    const int split = blockIdx.y;
    const int kPer = K / nsplit;
    const int c0 = split * kPer, c1 = c0 + kPer;
    const int ldRow = tid >> 2;
    const int ldCol = (tid & 3) * 4;

    float bestD[8]; int bestI[8];
#pragma unroll
    for (int i = 0; i < 8; ++i) { bestD[i] = 3.4e38f; bestI[i] = 0; }

    for (int ct = c0; ct < c1; ct += BN) {
        float acc[8][16];
#pragma unroll
        for (int i = 0; i < 8; ++i)
#pragma unroll
            for (int j = 0; j < 16; ++j) acc[i][j] = 0.f;

        for (int dt = 0; dt < D_DIM; dt += BD) {
#pragma unroll
            for (int p = 0; p < 4; ++p) {
                int r = ldRow + p * 32;
                float4 av = *(const float4*)&X[(size_t)(rowBase + r) * D_DIM + dt + ldCol];
                float4 bv = *(const float4*)&CB[(size_t)(ct + r) * D_DIM + dt + ldCol];
                As[ldCol + 0][r] = av.x; As[ldCol + 1][r] = av.y;
                As[ldCol + 2][r] = av.z; As[ldCol + 3][r] = av.w;
                Bs[ldCol + 0][r] = bv.x; Bs[ldCol + 1][r] = bv.y;
                Bs[ldCol + 2][r] = bv.z; Bs[ldCol + 3][r] = bv.w;
            }
            __syncthreads();
#pragma unroll
            for (int d = 0; d < BD; ++d) {
                float4 a0 = *(const float4*)&As[d][ty * 4];
                float4 a1 = *(const float4*)&As[d][64 + ty * 4];
                float4 b0 = *(const float4*)&Bs[d][ 0 + tx * 4];
                float4 b1 = *(const float4*)&Bs[d][32 + tx * 4];
                float4 b2 = *(const float4*)&Bs[d][64 + tx * 4];
                float4 b3 = *(const float4*)&Bs[d][96 + tx * 4];
                float a[8] = {a0.x,a0.y,a0.z,a0.w,a1.x,a1.y,a1.z,a1.w};
                float b[16] = {b0.x,b0.y,b0.z,b0.w, b1.x,b1.y,b1.z,b1.w,
                               b2.x,b2.y,b2.z,b2.w, b3.x,b3.y,b3.z,b3.w};
#pragma unroll
                for (int i = 0; i < 8; ++i)
#pragma unroll
                    for (int j = 0; j < 16; ++j)
                        acc[i][j] = fmaf(a[i], b[j], acc[i][j]);
            }
            __syncthreads();
        }
#pragma unroll
        for (int j = 0; j < 16; ++j) {
            int code = ct + (j >> 2) * 32 + tx * 4 + (j & 3);
            float c2v = cbs[code];
#pragma unroll
            for (int i = 0; i < 8; ++i) {
                float dist = fmaf(-2.f, acc[i][j], c2v);
                if (dist < bestD[i]) { bestD[i] = dist; bestI[i] = code; }
            }
        }
    }
#pragma unroll
    for (int i = 0; i < 8; ++i) {
        float bd = bestD[i]; int bi = bestI[i];
#pragma unroll
        for (int off = 1; off < 8; off <<= 1) {
            float od = __shfl_xor(bd, off);
            int   oi = __shfl_xor(bi, off);
            if (od < bd || (od == bd && oi < bi)) { bd = od; bi = oi; }
        }
        if (tx == 0) {
            int row = rowBase + ((i < 4) ? ty * 4 + i : 64 + ty * 4 + (i - 4));
            if (nsplit == 1) out[row] = bi;
            else {
                pd[(size_t)row * nsplit + split] = bd;
                pi[(size_t)row * nsplit + split] = bi;
            }
        }
    }
}

__global__ __launch_bounds__(256) void combine_fp32_kernel(
        const float* __restrict__ pd, const int* __restrict__ pi,
        int* __restrict__ out, int N, int S) {
    int r = blockIdx.x * blockDim.x + threadIdx.x;
    if (r >= N) return;
    float bd = pd[(size_t)r * S];
    int bi = pi[(size_t)r * S];
    for (int s = 1; s < S; ++s) {
        float d = pd[(size_t)r * S + s];
        int i = pi[(size_t)r * S + s];
        if (d < bd || (d == bd && i < bi)) { bd = d; bi = i; }
    }
    out[r] = bi;
}

// =========================== launcher ===========================
extern "C" void kernel_launch(void* const* d_in, const int* in_sizes, int n_in,
                              void* d_out, int out_size, void* d_ws, size_t ws_size,
                              hipStream_t stream) {
    const float* X  = (const float*)d_in[0];
    const float* CB = (const float*)d_in[1];
    const int N = in_sizes[0] / D_DIM;
    const int K = in_sizes[1] / D_DIM;
    int* out = (int*)d_out;

    size_t o = 0;
    auto take = [&](size_t bytes) { size_t r = o; o += (bytes + 255) & ~(size_t)255; return r; };
    size_t oCbs = take((size_t)K * 4);
    size_t oXT  = take((size_t)N * D_DIM * 2);
    size_t oCh  = take((size_t)K * D_DIM * 2);
    size_t oPd1 = take((size_t)N * KSPLIT * 4);
    size_t oPi1 = take((size_t)N * KSPLIT * 4);
    size_t oPd2 = take((size_t)N * KSPLIT * 4);
    size_t oPi2 = take((size_t)N * KSPLIT * 4);
    size_t oPd3 = take((size_t)N * KSPLIT * 4);
    size_t oFlg = take((size_t)N * 4);
    size_t oCnt = take(256);
    size_t oScD = take((size_t)N * 32 * 4);
    size_t oScI = take((size_t)N * 32 * 4);
    const size_t need = o;

    char* ws = (char*)d_ws;
    float* cbs = (float*)(ws + oCbs);

    if (ws_size >= need && (N % 256) == 0 && (K % (KSPLIT * 256)) == 0 &&
        (K % 32) == 0) {
        _Float16* XT = (_Float16*)(ws + oXT);
        _Float16* Ch = (_Float16*)(ws + oCh);
        float* pd1 = (float*)(ws + oPd1);
        int*   pi1 = (int*)(ws + oPi1);
        float* pd2 = (float*)(ws + oPd2);
        int*   pi2 = (int*)(ws + oPi2);
        float* pd3 = (float*)(ws + oPd3);
        int* flags = (int*)(ws + oFlg);
        int* cnt   = (int*)(ws + oCnt);
        float* scrD = (float*)(ws + oScD);
        int*   scrI = (int*)(ws + oScI);

        const int cbBlocks = K / 4;
        const int xTiles   = N / 64;
        prep_kernel<<<cbBlocks + xTiles, 256, 0, stream>>>(
            X, CB, XT, Ch, cbs, cnt, K, cbBlocks);

        vq_mfma_kernel<<<(N / 256) * KSPLIT, 512, 0, stream>>>(
            XT, Ch, cbs, pd1, pi1, pd2, pi2, pd3, N, K);

        combine_kernel<<<N / 256, 256, 0, stream>>>(
            X, CB, cbs, pd1, pi1, pd2, pi2, pd3, out, flags, cnt, N, KSPLIT);

        rare_scan_kernel<<<1024, 256, 0, stream>>>(
            X, CB, cbs, flags, cnt, scrD, scrI, K);

        rare_write_kernel<<<32, 256, 0, stream>>>(flags, cnt, scrD, scrI, out);
    } else {
        size_t base = ((size_t)K * 4 + 255) & ~(size_t)255;
        int nsplit = 4;
        while (nsplit > 1 &&
               (ws_size < base + (size_t)N * nsplit * 8 || (K % (nsplit * BN)) != 0))
            nsplit >>= 1;
        float* pd = (float*)(ws + base);
        int*   pi = (int*)(ws + base + (size_t)N * nsplit * 4);
        cbsqr_kernel<<<(K + 3) / 4, 256, 0, stream>>>(CB, cbs, K);
        dim3 grid(N / BM, nsplit);
        vq_fp32_kernel<<<grid, 128, 0, stream>>>(X, CB, cbs, pd, pi, out, N, K, nsplit);
        if (nsplit > 1)
            combine_fp32_kernel<<<(N + 255) / 256, 256, 0, stream>>>(pd, pi, out, N, nsplit);
    }
}

// Round 13
// 600.752 us; speedup vs baseline: 1.1095x; 1.1095x over previous
//
#include <hip/hip_runtime.h>

// VQ nearest-neighbor: argmin_k ||c_k||^2 - 2 x_n . c_k
// N=32768 rows, K=8192 codes, D=512, fp32 in, int32 indices out.
//
// Round 13: ZERO-barrier, zero-LDS-tile vq kernel. r8(2 bar) ~= r12(1 bar)
// proved sync-count isn't the lever; the lockstep {wait,barrier,read,MFMA}
// structure at 1 block/CU exposes every latency (~4700 cyc/step non-MFMA).
// Now BOTH operands are pre-transposed in global ([tile64][octet][elem64],
// fp16; C scaled x4096) and each wave register-prefetches next step's
// 8 cv + 4 xv b128 fragments, free-running with no s_barrier / manual
// vmcnt at all. cbs staged to LDS once at entry (fold off the vmcnt
// queue). Cost: C reads duplicated 4x, X 2x across waves -- L1/L2-served.
// top-3 + exact-refine tail unchanged from r12.

#define D_DIM 512
#define EPS_GAP 0.082f     // scaled (4096x) units = 2e-5 unscaled
#define KSPLIT 8

typedef __attribute__((ext_vector_type(16))) float f32x16;
typedef _Float16 half8v __attribute__((ext_vector_type(8)));

__device__ __forceinline__ void ins3(float d, int i, float& d1, int& i1,
                                     float& d2, int& i2, float& d3) {
    if (d < d1 || (d == d1 && i < i1)) { d3 = d2; d2 = d1; i2 = i1; d1 = d; i1 = i; }
    else if (d < d2 || (d == d2 && i < i2)) { d3 = d2; d2 = d; i2 = i; }
    else if (d < d3) d3 = d;
}

// ---- pass 0: CB -> CT (transposed, x4096 fp16) + ||c||^2; X -> XT ----
// T layout (16B half8v units): idx = (row/64)*4096 + octet*64 + (row%64),
// octet = k/8 (64 octets over D=512).
__global__ __launch_bounds__(256) void prep_kernel(
        const float* __restrict__ X, const float* __restrict__ CB,
        _Float16* __restrict__ XT, _Float16* __restrict__ CT,
        float* __restrict__ cbs, int* __restrict__ cnt,
        int K, int cbBlocks) {
    const int bid = blockIdx.x;
    const int tid = threadIdx.x;
    if (bid == 0 && tid == 0) *cnt = 0;
    if (bid < cbBlocks) {
        // wave per code row: lane = octet. Coalesced read; scattered 16B
        // CT writes (64 per wave, 1KB apart) -- L2 absorbs.
        int w = bid * 4 + (tid >> 6);
        int lane = tid & 63;
        if (w >= K) return;
        size_t base = (size_t)w * D_DIM + lane * 8;
        const float4* r4 = (const float4*)(CB + base);
        float4 u = r4[0], v = r4[1];
        float s = u.x*u.x + u.y*u.y + u.z*u.z + u.w*u.w
                + v.x*v.x + v.y*v.y + v.z*v.z + v.w*v.w;
        half8v h;
        h[0] = (_Float16)(u.x * 4096.f); h[1] = (_Float16)(u.y * 4096.f);
        h[2] = (_Float16)(u.z * 4096.f); h[3] = (_Float16)(u.w * 4096.f);
        h[4] = (_Float16)(v.x * 4096.f); h[5] = (_Float16)(v.y * 4096.f);
        h[6] = (_Float16)(v.z * 4096.f); h[7] = (_Float16)(v.w * 4096.f);
        ((half8v*)CT)[(w >> 6) * 4096 + lane * 64 + (w & 63)] = h;
#pragma unroll
        for (int off = 32; off; off >>= 1) s += __shfl_xor(s, off);
        if (lane == 0) cbs[w] = s;
    } else {
        // X transpose: block handles one 64-row tile.
        const int tile = bid - cbBlocks;
        const int o  = tid & 63;
        const int rq = tid >> 6;
        half8v* XT8 = (half8v*)XT;
#pragma unroll 4
        for (int rr = 0; rr < 16; ++rr) {
            int r = rq * 16 + rr;
            size_t src = (size_t)(tile * 64 + r) * D_DIM + o * 8;
            float4 a = *(const float4*)&X[src];
            float4 b = *(const float4*)&X[src + 4];
            half8v h;
            h[0] = (_Float16)a.x; h[1] = (_Float16)a.y;
            h[2] = (_Float16)a.z; h[3] = (_Float16)a.w;
            h[4] = (_Float16)b.x; h[5] = (_Float16)b.y;
            h[6] = (_Float16)b.z; h[7] = (_Float16)b.w;
            XT8[tile * 4096 + o * 64 + r] = h;
        }
    }
}

// ---- pass 1: barrier-free fp16 MFMA dists + per-lane top-3 ----
// grid = (N/256)*KSPLIT, 512 threads (8 waves: wr 2 x wcq 4). Each wave
// owns 128 codes x 64 xrows and free-runs on global operand fragments.
__global__ __launch_bounds__(512, 2) void vq_mfma_kernel(
        const _Float16* __restrict__ XT, const _Float16* __restrict__ CT,
        const float* __restrict__ cbs,
        float* __restrict__ pd1, int* __restrict__ pi1,
        float* __restrict__ pd2, int* __restrict__ pi2,
        float* __restrict__ pd3, int N, int K) {

    __shared__ float cbsS[1024];       // split's ||c||^2 slice
    __shared__ float mrg[1280];        // final cross-wr merge buffer

    const int tid  = threadIdx.x;
    const int lane = tid & 63;
    const int w    = tid >> 6;
    const int wr   = w >> 2;       // code half
    const int wcq  = w & 3;        // x quad
    const int bid  = blockIdx.x;
    const int split     = bid & (KSPLIT - 1);
    const int rowBase   = (bid >> 3) * 256;
    const int kPerSplit = K / KSPLIT;
    const int splitBase = split * kPerSplit;
    const int NT        = kPerSplit / 256;
    const int nSteps    = NT * 16;

    for (int i = tid; i < kPerSplit; i += 512) cbsS[i] = cbs[splitBase + i];
    __syncthreads();

    const half8v* XT8 = (const half8v*)XT;
    const half8v* CT8 = (const half8v*)CT;
    const int lhl = lane & 31;
    const int lh  = lane >> 5;
    // fragment (mf,kh) at (ct,kt): CT8[cbTile(ct,mf)*4096 + o*64 + (mf&1)*32
    //   + lhl], o = kt*4 + kh*2 + lh; cbTile = splitBase/64 + ct*4 + wr*2 + (mf>>1)
    const int cb00 = ((splitBase >> 6) + wr * 2) * 4096 + lh * 64 + lhl;
    const int xb0  = ((rowBase >> 6) + wcq) * 4096 + lh * 64 + lhl;

    float d1v[2], d2v[2], d3v[2];
    int   i1v[2], i2v[2];
#pragma unroll
    for (int nf = 0; nf < 2; ++nf) {
        d1v[nf] = 3.4e38f; d2v[nf] = 3.4e38f; d3v[nf] = 3.4e38f;
        i1v[nf] = 0x7fffffff; i2v[nf] = 0x7fffffff;
    }

    f32x16 acc[4][2];

    auto fold = [&](int ctF) {
        const int cl0 = ctF * 256 + wr * 128 + 4 * lh;
#pragma unroll
        for (int mf = 0; mf < 4; ++mf)
#pragma unroll
            for (int rq = 0; rq < 4; ++rq) {
                float4 c2q = *(const float4*)&cbsS[cl0 + mf * 32 + rq * 8];
#pragma unroll
                for (int j = 0; j < 4; ++j) {
                    const int code = splitBase + cl0 + mf * 32 + rq * 8 + j;
                    const int reg  = rq * 4 + j;
                    const float c2 = (&c2q.x)[j] * 4096.f;
#pragma unroll
                    for (int nf = 0; nf < 2; ++nf) {
                        float dist = fmaf(-2.f, acc[mf][nf][reg], c2);
                        ins3(dist, code, d1v[nf], i1v[nf], d2v[nf], i2v[nf], d3v[nf]);
                    }
                }
            }
    };

    half8v cvC[4][2], cvN[4][2], xvC[2][2], xvN[2][2];

    // prologue: fragments for s=0 (ct=0, kt=0)
#pragma unroll
    for (int mf = 0; mf < 4; ++mf)
#pragma unroll
        for (int kh = 0; kh < 2; ++kh)
            cvC[mf][kh] = CT8[cb00 + (mf >> 1) * 4096 + (kh * 2) * 64 + (mf & 1) * 32];
#pragma unroll
    for (int nf = 0; nf < 2; ++nf)
#pragma unroll
        for (int kh = 0; kh < 2; ++kh)
            xvC[nf][kh] = XT8[xb0 + (kh * 2) * 64 + nf * 32];

    for (int s = 0; s < nSteps; ++s) {
        const int kt = s & 15;
        const int ct = s >> 4;

        if (s + 1 < nSteps) {           // prefetch next step's fragments
            const int kt1 = (s + 1) & 15;
            const int ct1 = (s + 1) >> 4;
            const int cb1 = cb00 + ct1 * 4 * 4096 + kt1 * 4 * 64;
            const int xb1 = xb0 + kt1 * 4 * 64;
#pragma unroll
            for (int mf = 0; mf < 4; ++mf)
#pragma unroll
                for (int kh = 0; kh < 2; ++kh)
                    cvN[mf][kh] = CT8[cb1 + (mf >> 1) * 4096 + kh * 128 + (mf & 1) * 32];
#pragma unroll
            for (int nf = 0; nf < 2; ++nf)
#pragma unroll
                for (int kh = 0; kh < 2; ++kh)
                    xvN[nf][kh] = XT8[xb1 + kh * 128 + nf * 32];
        }

        if (kt == 0) {                  // fold prev code-tile (LDS cbs), reset acc
            if (s) fold(ct - 1);
#pragma unroll
            for (int mf = 0; mf < 4; ++mf)
#pragma unroll
                for (int nf = 0; nf < 2; ++nf)
#pragma unroll
                    for (int r = 0; r < 16; ++r) acc[mf][nf][r] = 0.f;
        }

#pragma unroll
        for (int kh = 0; kh < 2; ++kh)
#pragma unroll
            for (int mf = 0; mf < 4; ++mf)
#pragma unroll
                for (int nf = 0; nf < 2; ++nf)
                    acc[mf][nf] = __builtin_amdgcn_mfma_f32_32x32x16_f16(
                        cvC[mf][kh], xvC[nf][kh], acc[mf][nf], 0, 0, 0);

#pragma unroll
        for (int mf = 0; mf < 4; ++mf)
#pragma unroll
            for (int kh = 0; kh < 2; ++kh)
                cvC[mf][kh] = cvN[mf][kh];
#pragma unroll
        for (int nf = 0; nf < 2; ++nf)
#pragma unroll
            for (int kh = 0; kh < 2; ++kh)
                xvC[nf][kh] = xvN[nf][kh];
    }

    fold(NT - 1);

    // merge lane halves (l <-> l^32): same x-col, codes offset by 4*lh
#pragma unroll
    for (int nf = 0; nf < 2; ++nf) {
        float od1 = __shfl_xor(d1v[nf], 32);
        int   oi1 = __shfl_xor(i1v[nf], 32);
        float od2 = __shfl_xor(d2v[nf], 32);
        int   oi2 = __shfl_xor(i2v[nf], 32);
        float od3 = __shfl_xor(d3v[nf], 32);
        ins3(od1, oi1, d1v[nf], i1v[nf], d2v[nf], i2v[nf], d3v[nf]);
        ins3(od2, oi2, d1v[nf], i1v[nf], d2v[nf], i2v[nf], d3v[nf]);
        d3v[nf] = fminf(d3v[nf], od3);
    }

    // cross-wr merge via small LDS buffer
    __syncthreads();
    float* mD1 = mrg;
    int*   mI1 = (int*)(mrg + 256);
    float* mD2 = mrg + 512;
    int*   mI2 = (int*)(mrg + 768);
    float* mD3 = mrg + 1024;
    if (wr == 1 && lane < 32) {
#pragma unroll
        for (int nf = 0; nf < 2; ++nf) {
            int x = wcq * 64 + nf * 32 + lhl;
            mD1[x] = d1v[nf]; mI1[x] = i1v[nf];
            mD2[x] = d2v[nf]; mI2[x] = i2v[nf];
            mD3[x] = d3v[nf];
        }
    }
    __syncthreads();
    if (wr == 0 && lane < 32) {
#pragma unroll
        for (int nf = 0; nf < 2; ++nf) {
            int x = wcq * 64 + nf * 32 + lhl;
            float d1 = d1v[nf], d2 = d2v[nf], d3 = d3v[nf];
            int i1 = i1v[nf], i2 = i2v[nf];
            ins3(mD1[x], mI1[x], d1, i1, d2, i2, d3);
            ins3(mD2[x], mI2[x], d1, i1, d2, i2, d3);
            d3 = fminf(d3, mD3[x]);
            size_t p = (size_t)split * N + (rowBase + x);
            pd1[p] = d1; pi1[p] = i1; pd2[p] = d2; pi2[p] = i2; pd3[p] = d3;
        }
    }
}

// ---- pass 2: merge splits; 2-way ties inline exact; 3-way -> flag list ----
__global__ __launch_bounds__(256) void combine_kernel(
        const float* __restrict__ X, const float* __restrict__ CB,
        const float* __restrict__ cbs,
        const float* __restrict__ pd1, const int* __restrict__ pi1,
        const float* __restrict__ pd2, const int* __restrict__ pi2,
        const float* __restrict__ pd3,
        int* __restrict__ out, int* __restrict__ flags, int* __restrict__ cnt,
        int N, int S) {
    const int row = blockIdx.x * 256 + threadIdx.x;
    if (row >= N) return;
    float d1 = pd1[row], d2 = pd2[row], d3 = pd3[row];
    int i1 = pi1[row], i2 = pi2[row];
    for (int s = 1; s < S; ++s) {
        size_t p = (size_t)s * N + row;
        ins3(pd1[p], pi1[p], d1, i1, d2, i2, d3);
        ins3(pd2[p], pi2[p], d1, i1, d2, i2, d3);
        d3 = fminf(d3, pd3[p]);
    }
    int best = i1;
    if (d2 - d1 < EPS_GAP) {
        if (d3 - d1 < EPS_GAP) {
            int f = atomicAdd(cnt, 1);
            flags[f] = row;
        } else {
            const float4* xr = (const float4*)(X + (size_t)row * D_DIM);
            const float4* ca = (const float4*)(CB + (size_t)i1 * D_DIM);
            const float4* cb = (const float4*)(CB + (size_t)i2 * D_DIM);
            float dotA = 0.f, dotB = 0.f;
#pragma unroll 4
            for (int d = 0; d < D_DIM / 4; ++d) {
                float4 xv = xr[d], av = ca[d], bv = cb[d];
                dotA = fmaf(xv.x, av.x, dotA); dotA = fmaf(xv.y, av.y, dotA);
                dotA = fmaf(xv.z, av.z, dotA); dotA = fmaf(xv.w, av.w, dotA);
                dotB = fmaf(xv.x, bv.x, dotB); dotB = fmaf(xv.y, bv.y, dotB);
                dotB = fmaf(xv.z, bv.z, dotB); dotB = fmaf(xv.w, bv.w, dotB);
            }
            float dA = fmaf(-2.f, dotA, cbs[i1]);
            float dB = fmaf(-2.f, dotB, cbs[i2]);
            best = (dB < dA || (dB == dA && i2 < i1)) ? i2 : i1;
        }
    }
    out[row] = best;
}

// ---- pass 3: parallel exact scan of flagged rows (row x 32 chunks) ----
__global__ __launch_bounds__(256) void rare_scan_kernel(
        const float* __restrict__ X, const float* __restrict__ CB,
        const float* __restrict__ cbs,
        const int* __restrict__ flags, const int* __restrict__ cnt,
        float* __restrict__ scrD, int* __restrict__ scrI, int K) {
    __shared__ float xs[D_DIM];
    __shared__ float rD[4];
    __shared__ int   rI[4];
    const int nTasks = (*cnt) * 32;
    const int cpc = K / 32;
    for (int t = blockIdx.x; t < nTasks; t += gridDim.x) {
        const int fi = t >> 5, chunk = t & 31;
        const int row = flags[fi];
        __syncthreads();
        for (int i = threadIdx.x; i < D_DIM; i += 256)
            xs[i] = X[(size_t)row * D_DIM + i];
        __syncthreads();
        float bd = 3.4e38f; int bi = 0x7fffffff;
        for (int c = chunk * cpc + threadIdx.x; c < (chunk + 1) * cpc; c += 256) {
            const float4* cp = (const float4*)(CB + (size_t)c * D_DIM);
            float dot = 0.f;
#pragma unroll 4
            for (int d = 0; d < D_DIM / 4; ++d) {
                float4 cv = cp[d];
                float4 xv = *(const float4*)&xs[d * 4];
                dot = fmaf(xv.x, cv.x, dot); dot = fmaf(xv.y, cv.y, dot);
                dot = fmaf(xv.z, cv.z, dot); dot = fmaf(xv.w, cv.w, dot);
            }
            float dist = fmaf(-2.f, dot, cbs[c]);
            if (dist < bd || (dist == bd && c < bi)) { bd = dist; bi = c; }
        }
#pragma unroll
        for (int off = 1; off < 64; off <<= 1) {
            float od = __shfl_xor(bd, off);
            int   oi = __shfl_xor(bi, off);
            if (od < bd || (od == bd && oi < bi)) { bd = od; bi = oi; }
        }
        if ((threadIdx.x & 63) == 0) { rD[threadIdx.x >> 6] = bd; rI[threadIdx.x >> 6] = bi; }
        __syncthreads();
        if (threadIdx.x == 0) {
            for (int ww = 1; ww < 4; ++ww)
                if (rD[ww] < bd || (rD[ww] == bd && rI[ww] < bi)) {
                    bd = rD[ww]; bi = rI[ww];
                }
            scrD[t] = bd; scrI[t] = bi;
        }
    }
}

// ---- pass 4: reduce 32 chunk partials per flagged row ----
__global__ __launch_bounds__(256) void rare_write_kernel(
        const int* __restrict__ flags, const int* __restrict__ cnt,
        const float* __restrict__ scrD, const int* __restrict__ scrI,
        int* __restrict__ out) {
    const int nf = *cnt;
    for (int fi = blockIdx.x * 256 + threadIdx.x; fi < nf;
         fi += gridDim.x * 256) {
        float bd = scrD[fi * 32]; int bi = scrI[fi * 32];
        for (int ch = 1; ch < 32; ++ch) {
            float d = scrD[fi * 32 + ch]; int i = scrI[fi * 32 + ch];
            if (d < bd || (d == bd && i < bi)) { bd = d; bi = i; }
        }
        out[flags[fi]] = bi;
    }
}

// ================= fp32 fallback (generic shapes) =================
#define BM 128
#define BN 128
#define BD 16

__global__ __launch_bounds__(256) void cbsqr_kernel(const float* __restrict__ cb,
                                                    float* __restrict__ out, int K) {
    int gtid = blockIdx.x * blockDim.x + threadIdx.x;
    int w = gtid >> 6;
    int lane = gtid & 63;
    if (w >= K) return;
    const float4* r4 = (const float4*)(cb + (size_t)w * D_DIM) + lane * 2;
    float4 u = r4[0], v = r4[1];
    float s = u.x*u.x + u.y*u.y + u.z*u.z + u.w*u.w
            + v.x*v.x + v.y*v.y + v.z*v.z + v.w*v.w;
#pragma unroll
    for (int off = 32; off; off >>= 1) s += __shfl_xor(s, off);
    if (lane == 0) out[w] = s;
}

__global__ __launch_bounds__(128) void vq_fp32_kernel(
        const float* __restrict__ X, const float* __restrict__ CB,
        const float* __restrict__ cbs,
        float* __restrict__ pd, int* __restrict__ pi,
        int* __restrict__ out, int N, int K, int nsplit) {

    __shared__ float As[BD][BM + 4];
    __shared__ float Bs[BD][BN + 4];

    const int tid = threadIdx.x;
    const int tx = tid & 7;
    const int ty = tid >> 3;
    const int rowBase = blockIdx.x * BM;
    const int split = blockIdx.y;
    const int kPer = K / nsplit;
    const int c0 = split * kPer, c1 = c0 + kPer;
    const int ldRow = tid >> 2;
    const int ldCol = (tid & 3) * 4;

    float bestD[8]; int bestI[8];
#pragma unroll
    for (int i = 0; i < 8; ++i) { bestD[i] = 3.4e38f; bestI[i] = 0; }

    for (int ct = c0; ct < c1; ct += BN) {
        float acc[8][16];
#pragma unroll
        for (int i = 0; i < 8; ++i)
#pragma unroll
            for (int j = 0; j < 16; ++j) acc[i][j] = 0.f;

        for (int dt = 0; dt < D_DIM; dt += BD) {
#pragma unroll
            for (int p = 0; p < 4; ++p) {
                int r = ldRow + p * 32;
                float4 av = *(const float4*)&X[(size_t)(rowBase + r) * D_DIM + dt + ldCol];
                float4 bv = *(const float4*)&CB[(size_t)(ct + r) * D_DIM + dt + ldCol];
                As[ldCol + 0][r] = av.x; As[ldCol + 1][r] = av.y;
                As[ldCol + 2][r] = av.z; As[ldCol + 3][r] = av.w;
                Bs[ldCol + 0][r] = bv.x; Bs[ldCol + 1][r] = bv.y;
                Bs[ldCol + 2][r] = bv.z; Bs[ldCol + 3][r] = bv.w;
            }
            __syncthreads();
#pragma unroll
            for (int d = 0; d < BD; ++d) {
                float4 a0 = *(const float4*)&As[d][ty * 4];
                float4 a1 = *(const float4*)&As[d][64 + ty * 4];
                float4 b0 = *(const float4*)&Bs[d][ 0 + tx * 4];
                float4 b1 = *(const float4*)&Bs[d][32 + tx * 4];
                float4 b2 = *(const float4*)&Bs[d][64 + tx * 4];
                float4 b3 = *(const float4*)&Bs[d][96 + tx * 4];
                float a[8] = {a0.x,a0.y,a0.z,a0.w,a1.x,a1.y,a1.z,a1.w};
                float b[16] = {b0.x,b0.y,b0.z,b0.w, b1.x,b1.y,b1.z,b1.w,
                               b2.x,b2.y,b2.z,b2.w, b3.x,b3.y,b3.z,b3.w};
#pragma unroll
                for (int i = 0; i < 8; ++i)
#pragma unroll
                    for (int j = 0; j < 16; ++j)
                        acc[i][j] = fmaf(a[i], b[j], acc[i][j]);
            }
            __syncthreads();
        }
#pragma unroll
        for (int j = 0; j < 16; ++j) {
            int code = ct + (j >> 2) * 32 + tx * 4 + (j & 3);
            float c2v = cbs[code];
#pragma unroll
            for (int i = 0; i < 8; ++i) {
                float dist = fmaf(-2.f, acc[i][j], c2v);
                if (dist < bestD[i]) { bestD[i] = dist; bestI[i] = code; }
            }
        }
    }
#pragma unroll
    for (int i = 0; i < 8; ++i) {
        float bd = bestD[i]; int bi = bestI[i];
#pragma unroll
        for (int off = 1; off < 8; off <<= 1) {
            float od = __shfl_xor(bd, off);
            int   oi = __shfl_xor(bi, off);
            if (od < bd || (od == bd && oi < bi)) { bd = od; bi = oi; }
        }
        if (tx == 0) {
            int row = rowBase + ((i < 4) ? ty * 4 + i : 64 + ty * 4 + (i - 4));
            if (nsplit == 1) out[row] = bi;
            else {
                pd[(size_t)row * nsplit + split] = bd;
                pi[(size_t)row * nsplit + split] = bi;
            }
        }
    }
}

__global__ __launch_bounds__(256) void combine_fp32_kernel(
        const float* __restrict__ pd, const int* __restrict__ pi,
        int* __restrict__ out, int N, int S) {
    int r = blockIdx.x * blockDim.x + threadIdx.x;
    if (r >= N) return;
    float bd = pd[(size_t)r * S];
    int bi = pi[(size_t)r * S];
    for (int s = 1; s < S; ++s) {
        float d = pd[(size_t)r * S + s];
        int i = pi[(size_t)r * S + s];
        if (d < bd || (d == bd && i < bi)) { bd = d; bi = i; }
    }
    out[r] = bi;
}

// =========================== launcher ===========================
extern "C" void kernel_launch(void* const* d_in, const int* in_sizes, int n_in,
                              void* d_out, int out_size, void* d_ws, size_t ws_size,
                              hipStream_t stream) {
    const float* X  = (const float*)d_in[0];
    const float* CB = (const float*)d_in[1];
    const int N = in_sizes[0] / D_DIM;
    const int K = in_sizes[1] / D_DIM;
    int* out = (int*)d_out;

    size_t o = 0;
    auto take = [&](size_t bytes) { size_t r = o; o += (bytes + 255) & ~(size_t)255; return r; };
    size_t oCbs = take((size_t)K * 4);
    size_t oXT  = take((size_t)N * D_DIM * 2);
    size_t oCT  = take((size_t)K * D_DIM * 2);
    size_t oPd1 = take((size_t)N * KSPLIT * 4);
    size_t oPi1 = take((size_t)N * KSPLIT * 4);
    size_t oPd2 = take((size_t)N * KSPLIT * 4);
    size_t oPi2 = take((size_t)N * KSPLIT * 4);
    size_t oPd3 = take((size_t)N * KSPLIT * 4);
    size_t oFlg = take((size_t)N * 4);
    size_t oCnt = take(256);
    size_t oScD = take((size_t)N * 32 * 4);
    size_t oScI = take((size_t)N * 32 * 4);
    const size_t need = o;

    char* ws = (char*)d_ws;
    float* cbs = (float*)(ws + oCbs);

    if (ws_size >= need && (N % 256) == 0 && (K % (KSPLIT * 256)) == 0 &&
        (K % 32) == 0) {
        _Float16* XT = (_Float16*)(ws + oXT);
        _Float16* CT = (_Float16*)(ws + oCT);
        float* pd1 = (float*)(ws + oPd1);
        int*   pi1 = (int*)(ws + oPi1);
        float* pd2 = (float*)(ws + oPd2);
        int*   pi2 = (int*)(ws + oPi2);
        float* pd3 = (float*)(ws + oPd3);
        int* flags = (int*)(ws + oFlg);
        int* cnt   = (int*)(ws + oCnt);
        float* scrD = (float*)(ws + oScD);
        int*   scrI = (int*)(ws + oScI);

        const int cbBlocks = K / 4;
        const int xTiles   = N / 64;
        prep_kernel<<<cbBlocks + xTiles, 256, 0, stream>>>(
            X, CB, XT, CT, cbs, cnt, K, cbBlocks);

        vq_mfma_kernel<<<(N / 256) * KSPLIT, 512, 0, stream>>>(
            XT, CT, cbs, pd1, pi1, pd2, pi2, pd3, N, K);

        combine_kernel<<<N / 256, 256, 0, stream>>>(
            X, CB, cbs, pd1, pi1, pd2, pi2, pd3, out, flags, cnt, N, KSPLIT);

        rare_scan_kernel<<<1024, 256, 0, stream>>>(
            X, CB, cbs, flags, cnt, scrD, scrI, K);

        rare_write_kernel<<<32, 256, 0, stream>>>(flags, cnt, scrD, scrI, out);
    } else {
        size_t base = ((size_t)K * 4 + 255) & ~(size_t)255;
        int nsplit = 4;
        while (nsplit > 1 &&
               (ws_size < base + (size_t)N * nsplit * 8 || (K % (nsplit * BN)) != 0))
            nsplit >>= 1;
        float* pd = (float*)(ws + base);
        int*   pi = (int*)(ws + base + (size_t)N * nsplit * 4);
        cbsqr_kernel<<<(K + 3) / 4, 256, 0, stream>>>(CB, cbs, K);
        dim3 grid(N / BM, nsplit);
        vq_fp32_kernel<<<grid, 128, 0, stream>>>(X, CB, cbs, pd, pi, out, N, K, nsplit);
        if (nsplit > 1)
            combine_fp32_kernel<<<(N + 255) / 256, 256, 0, stream>>>(pd, pi, out, N, nsplit);
    }
}

// Round 14
// 579.526 us; speedup vs baseline: 1.1501x; 1.0366x over previous
//
#include <hip/hip_runtime.h>

// VQ nearest-neighbor: argmin_k ||c_k||^2 - 2 x_n . c_k
// N=32768 rows, K=8192 codes, D=512, fp32 in, int32 indices out.
//
// Round 14: BK=64 amortization. Cross-round data (r6: 7550 cyc/step @3100
// MFMA; r11: 5880 @1033; r13: 5250 @1033) shows ~4600 cyc/step FIXED
// overhead independent of in-step work -> double the work per step.
// r11 structure (LDS-shared tiles, counted vmcnt, 2 barriers) with
// 64-wide K-slices: 32 steps x {8 gloads -> vmcnt(8), 24 ds_read_b128,
// 32 MFMA in two setprio clusters}. 128B-row swizzle sw3(r) =
// ((r>>1)&7)^(((r>>4)&1)<<1), staging pre-swizzled at the global source
// (chunk c0=(lane&7)^(lane>>4), XOR {0,4,2,6} per sub-write), read chunk
// = octet ^ sw3l (lane-only). cbs staged to LDS once (vmcnt queue pure).
// fp16 single-GEMM + top-3 + parallel exact-refine tail unchanged.

#define D_DIM 512
#define EPS_GAP 0.082f     // scaled (4096x) units = 2e-5 unscaled
#define KSPLIT 8

typedef __attribute__((ext_vector_type(16))) float f32x16;
typedef _Float16 half8v __attribute__((ext_vector_type(8)));
typedef _Float16 half4v __attribute__((ext_vector_type(4)));

__device__ __forceinline__ void gload_lds16(const void* g, void* l) {
    __builtin_amdgcn_global_load_lds(
        (const __attribute__((address_space(1))) unsigned int*)g,
        (__attribute__((address_space(3))) unsigned int*)l, 16, 0, 0);
}

__device__ __forceinline__ void ins3(float d, int i, float& d1, int& i1,
                                     float& d2, int& i2, float& d3) {
    if (d < d1 || (d == d1 && i < i1)) { d3 = d2; d2 = d1; i2 = i1; d1 = d; i1 = i; }
    else if (d < d2 || (d == d2 && i < i2)) { d3 = d2; d2 = d; i2 = i; }
    else if (d < d3) d3 = d;
}

// ---- pass 0: CB -> fp16 (x4096) + ||c||^2 (wave/row); X -> fp16 ----
__global__ __launch_bounds__(256) void prep_kernel(
        const float* __restrict__ X, const float* __restrict__ CB,
        _Float16* __restrict__ Xh, _Float16* __restrict__ Ch,
        float* __restrict__ cbs, int* __restrict__ cnt,
        int n4, int K, int cbBlocks, int xBlocks) {
    const int bid = blockIdx.x;
    const int tid = threadIdx.x;
    if (bid == 0 && tid == 0) *cnt = 0;
    if (bid < cbBlocks) {
        int w = bid * 4 + (tid >> 6);
        int lane = tid & 63;
        if (w >= K) return;
        size_t base = (size_t)w * D_DIM + lane * 8;
        const float4* r4 = (const float4*)(CB + base);
        float4 u = r4[0], v = r4[1];
        float s = u.x*u.x + u.y*u.y + u.z*u.z + u.w*u.w
                + v.x*v.x + v.y*v.y + v.z*v.z + v.w*v.w;
        half8v h;
        h[0] = (_Float16)(u.x * 4096.f); h[1] = (_Float16)(u.y * 4096.f);
        h[2] = (_Float16)(u.z * 4096.f); h[3] = (_Float16)(u.w * 4096.f);
        h[4] = (_Float16)(v.x * 4096.f); h[5] = (_Float16)(v.y * 4096.f);
        h[6] = (_Float16)(v.z * 4096.f); h[7] = (_Float16)(v.w * 4096.f);
        *(half8v*)(Ch + base) = h;
#pragma unroll
        for (int off = 32; off; off >>= 1) s += __shfl_xor(s, off);
        if (lane == 0) cbs[w] = s;
    } else {
        int i = (bid - cbBlocks) * 256 + tid;
        int stride = xBlocks * 256;
        for (; i < n4; i += stride) {
            float4 v = ((const float4*)X)[i];
            half4v h;
            h[0] = (_Float16)v.x; h[1] = (_Float16)v.y;
            h[2] = (_Float16)v.z; h[3] = (_Float16)v.w;
            ((half4v*)Xh)[i] = h;
        }
    }
}

// ---- pass 1: fp16 MFMA dists + per-lane top-3, BK=64 per step ----
// grid = (N/256)*KSPLIT, 512 threads (8 waves: wr 2 x wcq 4).
__global__ __launch_bounds__(512, 2) void vq_mfma_kernel(
        const _Float16* __restrict__ Xh, const _Float16* __restrict__ Ch,
        const float* __restrict__ cbs,
        float* __restrict__ pd1, int* __restrict__ pi1,
        float* __restrict__ pd2, int* __restrict__ pi2,
        float* __restrict__ pd3, int N, int K) {

    __shared__ _Float16 Cs[2][256 * 64];   // 32KB per buf
    __shared__ _Float16 Xs[2][256 * 64];
    __shared__ float cbsS[1024];

    const int tid  = threadIdx.x;
    const int lane = tid & 63;
    const int w    = tid >> 6;
    const int wr   = w >> 2;       // code half
    const int wcq  = w & 3;        // x quad
    const int bid  = blockIdx.x;
    const int split     = bid & (KSPLIT - 1);
    const int rowBase   = (bid >> 3) * 256;
    const int kPerSplit = K / KSPLIT;
    const int splitBase = split * kPerSplit;
    const int NT        = kPerSplit / 256;
    const int nSteps    = NT * 8;          // BK=64

    for (int i = tid; i < kPerSplit; i += 512) cbsS[i] = cbs[splitBase + i];
    __syncthreads();

    // Staging: wave w covers tile rows w*32..+31; sub-write j (0..3) puts
    // rows j*8+(lane>>3), chunk lane&7 (linear LDS). Pre-swizzled global
    // source chunk = (lane&7)^(lane>>4) XOR {0,4,2,6}[j]  (= c ^ sw3(row)).
    const int c0 = (lane & 7) ^ (lane >> 4);
    const int rsub = lane >> 3;
    const int srcOff0 = (w * 32 + 0  + rsub) * D_DIM + (c0 ^ 0) * 8;
    const int srcOff1 = (w * 32 + 8  + rsub) * D_DIM + (c0 ^ 4) * 8;
    const int srcOff2 = (w * 32 + 16 + rsub) * D_DIM + (c0 ^ 2) * 8;
    const int srcOff3 = (w * 32 + 24 + rsub) * D_DIM + (c0 ^ 6) * 8;
    const int l0 = w * 2048 + lane * 8;    // LDS fp16 offset

    // Fragment reads: row = base + (lane&31); physical octet o = kh*2+lh;
    // chunk = o ^ sw3l, sw3l = (((lane&31)>>1)&7) ^ (((lane>>4)&1)<<1).
    const int lh  = lane >> 5;
    const int la  = lane & 31;
    const int sw3l = ((la >> 1) & 7) ^ (((lane >> 4) & 1) << 1);
    const int rC = wr * 128 + la;
    const int rX = wcq * 64 + la;
    const int kOff0 = ((0 + lh) ^ sw3l) * 8;
    const int kOff1 = ((2 + lh) ^ sw3l) * 8;
    const int kOff2 = ((4 + lh) ^ sw3l) * 8;
    const int kOff3 = ((6 + lh) ^ sw3l) * 8;

    float d1v[2], d2v[2], d3v[2];
    int   i1v[2], i2v[2];
#pragma unroll
    for (int nf = 0; nf < 2; ++nf) {
        d1v[nf] = 3.4e38f; d2v[nf] = 3.4e38f; d3v[nf] = 3.4e38f;
        i1v[nf] = 0x7fffffff; i2v[nf] = 0x7fffffff;
    }

    f32x16 acc[4][2];

    auto fold = [&](int ctF) {
        const int cl0 = ctF * 256 + wr * 128 + 4 * lh;
#pragma unroll
        for (int mf = 0; mf < 4; ++mf)
#pragma unroll
            for (int rq = 0; rq < 4; ++rq) {
                float4 c2q = *(const float4*)&cbsS[cl0 + mf * 32 + rq * 8];
#pragma unroll
                for (int j = 0; j < 4; ++j) {
                    const int code = splitBase + cl0 + mf * 32 + rq * 8 + j;
                    const int reg  = rq * 4 + j;
                    const float c2 = (&c2q.x)[j] * 4096.f;
#pragma unroll
                    for (int nf = 0; nf < 2; ++nf) {
                        float dist = fmaf(-2.f, acc[mf][nf][reg], c2);
                        ins3(dist, code, d1v[nf], i1v[nf], d2v[nf], i2v[nf], d3v[nf]);
                    }
                }
            }
    };

#define STAGE(buf, s_)                                                        \
    do { int ct_ = (s_) >> 3, kt_ = (s_) & 7;                                 \
        const _Float16* Cb_ = Ch + (size_t)(splitBase + ct_ * 256) * D_DIM    \
                              + kt_ * 64;                                     \
        const _Float16* Xb_ = Xh + (size_t)rowBase * D_DIM + kt_ * 64;        \
        gload_lds16(Cb_ + srcOff0, &Cs[buf][l0]);                             \
        gload_lds16(Cb_ + srcOff1, &Cs[buf][l0 + 512]);                       \
        gload_lds16(Cb_ + srcOff2, &Cs[buf][l0 + 1024]);                      \
        gload_lds16(Cb_ + srcOff3, &Cs[buf][l0 + 1536]);                      \
        gload_lds16(Xb_ + srcOff0, &Xs[buf][l0]);                             \
        gload_lds16(Xb_ + srcOff1, &Xs[buf][l0 + 512]);                       \
        gload_lds16(Xb_ + srcOff2, &Xs[buf][l0 + 1024]);                      \
        gload_lds16(Xb_ + srcOff3, &Xs[buf][l0 + 1536]);                      \
    } while (0)

    STAGE(0, 0);

    for (int s = 0; s < nSteps; ++s) {
        const int cur = s & 1;
        const int kt  = s & 7;
        const int ct  = s >> 3;

        if (s + 1 < nSteps) {
            STAGE(cur ^ 1, s + 1);
            // 8 loads/step: outstanding = 8 (cur, oldest) + 8 (next);
            // vmcnt(8) retires exactly the current step's loads.
            asm volatile("s_waitcnt vmcnt(8)" ::: "memory");
        } else {
            asm volatile("s_waitcnt vmcnt(0)" ::: "memory");
        }
        __builtin_amdgcn_s_barrier();          // cur buffers visible

        if (kt == 0) {                          // fold prev code-tile, reset acc
            if (s) fold(ct - 1);
#pragma unroll
            for (int mf = 0; mf < 4; ++mf)
#pragma unroll
                for (int nf = 0; nf < 2; ++nf)
#pragma unroll
                    for (int r = 0; r < 16; ++r) acc[mf][nf][r] = 0.f;
        }

        {   // cluster A: kh 0,1
            half8v xvA[2][2], cvA[4][2];
#pragma unroll
            for (int nf = 0; nf < 2; ++nf) {
                xvA[nf][0] = *(const half8v*)&Xs[cur][(rX + nf * 32) * 64 + kOff0];
                xvA[nf][1] = *(const half8v*)&Xs[cur][(rX + nf * 32) * 64 + kOff1];
            }
#pragma unroll
            for (int mf = 0; mf < 4; ++mf) {
                cvA[mf][0] = *(const half8v*)&Cs[cur][(rC + mf * 32) * 64 + kOff0];
                cvA[mf][1] = *(const half8v*)&Cs[cur][(rC + mf * 32) * 64 + kOff1];
            }
            __builtin_amdgcn_s_setprio(1);
#pragma unroll
            for (int kh = 0; kh < 2; ++kh)
#pragma unroll
                for (int mf = 0; mf < 4; ++mf)
#pragma unroll
                    for (int nf = 0; nf < 2; ++nf)
                        acc[mf][nf] = __builtin_amdgcn_mfma_f32_32x32x16_f16(
                            cvA[mf][kh], xvA[nf][kh], acc[mf][nf], 0, 0, 0);
            __builtin_amdgcn_s_setprio(0);
        }
        {   // cluster B: kh 2,3
            half8v xvB[2][2], cvB[4][2];
#pragma unroll
            for (int nf = 0; nf < 2; ++nf) {
                xvB[nf][0] = *(const half8v*)&Xs[cur][(rX + nf * 32) * 64 + kOff2];
                xvB[nf][1] = *(const half8v*)&Xs[cur][(rX + nf * 32) * 64 + kOff3];
            }
#pragma unroll
            for (int mf = 0; mf < 4; ++mf) {
                cvB[mf][0] = *(const half8v*)&Cs[cur][(rC + mf * 32) * 64 + kOff2];
                cvB[mf][1] = *(const half8v*)&Cs[cur][(rC + mf * 32) * 64 + kOff3];
            }
            __builtin_amdgcn_s_setprio(1);
#pragma unroll
            for (int kh = 0; kh < 2; ++kh)
#pragma unroll
                for (int mf = 0; mf < 4; ++mf)
#pragma unroll
                    for (int nf = 0; nf < 2; ++nf)
                        acc[mf][nf] = __builtin_amdgcn_mfma_f32_32x32x16_f16(
                            cvB[mf][kh], xvB[nf][kh], acc[mf][nf], 0, 0, 0);
            __builtin_amdgcn_s_setprio(0);
        }

        __builtin_amdgcn_sched_barrier(0);      // pin reads above end barrier
        __builtin_amdgcn_s_barrier();           // all reads of cur done
    }
#undef STAGE

    fold(NT - 1);

    // merge lane halves (l <-> l^32): same x-col, codes offset by 4*lh
#pragma unroll
    for (int nf = 0; nf < 2; ++nf) {
        float od1 = __shfl_xor(d1v[nf], 32);
        int   oi1 = __shfl_xor(i1v[nf], 32);
        float od2 = __shfl_xor(d2v[nf], 32);
        int   oi2 = __shfl_xor(i2v[nf], 32);
        float od3 = __shfl_xor(d3v[nf], 32);
        ins3(od1, oi1, d1v[nf], i1v[nf], d2v[nf], i2v[nf], d3v[nf]);
        ins3(od2, oi2, d1v[nf], i1v[nf], d2v[nf], i2v[nf], d3v[nf]);
        d3v[nf] = fminf(d3v[nf], od3);
    }

    // cross-wr merge via LDS overlay on Cs[0] (all tile reads done)
    __syncthreads();
    float* mD1 = (float*)&Cs[0][0];
    int*   mI1 = (int*)(mD1 + 256);
    float* mD2 = (float*)(mD1 + 512);
    int*   mI2 = (int*)(mD1 + 768);
    float* mD3 = (float*)(mD1 + 1024);
    if (wr == 1 && lane < 32) {
#pragma unroll
        for (int nf = 0; nf < 2; ++nf) {
            int x = wcq * 64 + nf * 32 + la;
            mD1[x] = d1v[nf]; mI1[x] = i1v[nf];
            mD2[x] = d2v[nf]; mI2[x] = i2v[nf];
            mD3[x] = d3v[nf];
        }
    }
    __syncthreads();
    if (wr == 0 && lane < 32) {
#pragma unroll
        for (int nf = 0; nf < 2; ++nf) {
            int x = wcq * 64 + nf * 32 + la;
            float d1 = d1v[nf], d2 = d2v[nf], d3 = d3v[nf];
            int i1 = i1v[nf], i2 = i2v[nf];
            ins3(mD1[x], mI1[x], d1, i1, d2, i2, d3);
            ins3(mD2[x], mI2[x], d1, i1, d2, i2, d3);
            d3 = fminf(d3, mD3[x]);
            size_t p = (size_t)split * N + (rowBase + x);
            pd1[p] = d1; pi1[p] = i1; pd2[p] = d2; pi2[p] = i2; pd3[p] = d3;
        }
    }
}

// ---- pass 2: merge splits; 2-way ties inline exact; 3-way -> flag list ----
__global__ __launch_bounds__(256) void combine_kernel(
        const float* __restrict__ X, const float* __restrict__ CB,
        const float* __restrict__ cbs,
        const float* __restrict__ pd1, const int* __restrict__ pi1,
        const float* __restrict__ pd2, const int* __restrict__ pi2,
        const float* __restrict__ pd3,
        int* __restrict__ out, int* __restrict__ flags, int* __restrict__ cnt,
        int N, int S) {
    const int row = blockIdx.x * 256 + threadIdx.x;
    if (row >= N) return;
    float d1 = pd1[row], d2 = pd2[row], d3 = pd3[row];
    int i1 = pi1[row], i2 = pi2[row];
    for (int s = 1; s < S; ++s) {
        size_t p = (size_t)s * N + row;
        ins3(pd1[p], pi1[p], d1, i1, d2, i2, d3);
        ins3(pd2[p], pi2[p], d1, i1, d2, i2, d3);
        d3 = fminf(d3, pd3[p]);
    }
    int best = i1;
    if (d2 - d1 < EPS_GAP) {
        if (d3 - d1 < EPS_GAP) {
            int f = atomicAdd(cnt, 1);
            flags[f] = row;
        } else {
            const float4* xr = (const float4*)(X + (size_t)row * D_DIM);
            const float4* ca = (const float4*)(CB + (size_t)i1 * D_DIM);
            const float4* cb = (const float4*)(CB + (size_t)i2 * D_DIM);
            float dotA = 0.f, dotB = 0.f;
#pragma unroll 4
            for (int d = 0; d < D_DIM / 4; ++d) {
                float4 xv = xr[d], av = ca[d], bv = cb[d];
                dotA = fmaf(xv.x, av.x, dotA); dotA = fmaf(xv.y, av.y, dotA);
                dotA = fmaf(xv.z, av.z, dotA); dotA = fmaf(xv.w, av.w, dotA);
                dotB = fmaf(xv.x, bv.x, dotB); dotB = fmaf(xv.y, bv.y, dotB);
                dotB = fmaf(xv.z, bv.z, dotB); dotB = fmaf(xv.w, bv.w, dotB);
            }
            float dA = fmaf(-2.f, dotA, cbs[i1]);
            float dB = fmaf(-2.f, dotB, cbs[i2]);
            best = (dB < dA || (dB == dA && i2 < i1)) ? i2 : i1;
        }
    }
    out[row] = best;
}

// ---- pass 3: parallel exact scan of flagged rows (row x 32 chunks) ----
__global__ __launch_bounds__(256) void rare_scan_kernel(
        const float* __restrict__ X, const float* __restrict__ CB,
        const float* __restrict__ cbs,
        const int* __restrict__ flags, const int* __restrict__ cnt,
        float* __restrict__ scrD, int* __restrict__ scrI, int K) {
    __shared__ float xs[D_DIM];
    __shared__ float rD[4];
    __shared__ int   rI[4];
    const int nTasks = (*cnt) * 32;
    const int cpc = K / 32;
    for (int t = blockIdx.x; t < nTasks; t += gridDim.x) {
        const int fi = t >> 5, chunk = t & 31;
        const int row = flags[fi];
        __syncthreads();
        for (int i = threadIdx.x; i < D_DIM; i += 256)
            xs[i] = X[(size_t)row * D_DIM + i];
        __syncthreads();
        float bd = 3.4e38f; int bi = 0x7fffffff;
        for (int c = chunk * cpc + threadIdx.x; c < (chunk + 1) * cpc; c += 256) {
            const float4* cp = (const float4*)(CB + (size_t)c * D_DIM);
            float dot = 0.f;
#pragma unroll 4
            for (int d = 0; d < D_DIM / 4; ++d) {
                float4 cv = cp[d];
                float4 xv = *(const float4*)&xs[d * 4];
                dot = fmaf(xv.x, cv.x, dot); dot = fmaf(xv.y, cv.y, dot);
                dot = fmaf(xv.z, cv.z, dot); dot = fmaf(xv.w, cv.w, dot);
            }
            float dist = fmaf(-2.f, dot, cbs[c]);
            if (dist < bd || (dist == bd && c < bi)) { bd = dist; bi = c; }
        }
#pragma unroll
        for (int off = 1; off < 64; off <<= 1) {
            float od = __shfl_xor(bd, off);
            int   oi = __shfl_xor(bi, off);
            if (od < bd || (od == bd && oi < bi)) { bd = od; bi = oi; }
        }
        if ((threadIdx.x & 63) == 0) { rD[threadIdx.x >> 6] = bd; rI[threadIdx.x >> 6] = bi; }
        __syncthreads();
        if (threadIdx.x == 0) {
            for (int ww = 1; ww < 4; ++ww)
                if (rD[ww] < bd || (rD[ww] == bd && rI[ww] < bi)) {
                    bd = rD[ww]; bi = rI[ww];
                }
            scrD[t] = bd; scrI[t] = bi;
        }
    }
}

// ---- pass 4: reduce 32 chunk partials per flagged row ----
__global__ __launch_bounds__(256) void rare_write_kernel(
        const int* __restrict__ flags, const int* __restrict__ cnt,
        const float* __restrict__ scrD, const int* __restrict__ scrI,
        int* __restrict__ out) {
    const int nf = *cnt;
    for (int fi = blockIdx.x * 256 + threadIdx.x; fi < nf;
         fi += gridDim.x * 256) {
        float bd = scrD[fi * 32]; int bi = scrI[fi * 32];
        for (int ch = 1; ch < 32; ++ch) {
            float d = scrD[fi * 32 + ch]; int i = scrI[fi * 32 + ch];
            if (d < bd || (d == bd && i < bi)) { bd = d; bi = i; }
        }
        out[flags[fi]] = bi;
    }
}

// ================= fp32 fallback (generic shapes) =================
#define BM 128
#define BN 128
#define BD 16

__global__ __launch_bounds__(256) void cbsqr_kernel(const float* __restrict__ cb,
                                                    float* __restrict__ out, int K) {
    int gtid = blockIdx.x * blockDim.x + threadIdx.x;
    int w = gtid >> 6;
    int lane = gtid & 63;
    if (w >= K) return;
    const float4* r4 = (const float4*)(cb + (size_t)w * D_DIM) + lane * 2;
    float4 u = r4[0], v = r4[1];
    float s = u.x*u.x + u.y*u.y + u.z*u.z + u.w*u.w
            + v.x*v.x + v.y*v.y + v.z*v.z + v.w*v.w;
#pragma unroll
    for (int off = 32; off; off >>= 1) s += __shfl_xor(s, off);
    if (lane == 0) out[w] = s;
}

__global__ __launch_bounds__(128) void vq_fp32_kernel(
        const float* __restrict__ X, const float* __restrict__ CB,
        const float* __restrict__ cbs,
        float* __restrict__ pd, int* __restrict__ pi,
        int* __restrict__ out, int N, int K, int nsplit) {

    __shared__ float As[BD][BM + 4];
    __shared__ float Bs[BD][BN + 4];

    const int tid = threadIdx.x;
    const int tx = tid & 7;
    const int ty = tid >> 3;
    const int rowBase = blockIdx.x * BM;
    const int split = blockIdx.y;
    const int kPer = K / nsplit;
    const int c0 = split * kPer, c1 = c0 + kPer;
    const int ldRow = tid >> 2;
    const int ldCol = (tid & 3) * 4;

    float bestD[8]; int bestI[8];
#pragma unroll
    for (int i = 0; i < 8; ++i) { bestD[i] = 3.4e38f; bestI[i] = 0; }

    for (int ct = c0; ct < c1; ct += BN) {
        float acc[8][16];
#pragma unroll
        for (int i = 0; i < 8; ++i)
#pragma unroll
            for (int j = 0; j < 16; ++j) acc[i][j] = 0.f;

        for (int dt = 0; dt < D_DIM; dt += BD) {
#pragma unroll
            for (int p = 0; p < 4; ++p) {
                int r = ldRow + p * 32;
                float4 av = *(const float4*)&X[(size_t)(rowBase + r) * D_DIM + dt + ldCol];
                float4 bv = *(const float4*)&CB[(size_t)(ct + r) * D_DIM + dt + ldCol];
                As[ldCol + 0][r] = av.x; As[ldCol + 1][r] = av.y;
                As[ldCol + 2][r] = av.z; As[ldCol + 3][r] = av.w;
                Bs[ldCol + 0][r] = bv.x; Bs[ldCol + 1][r] = bv.y;
                Bs[ldCol + 2][r] = bv.z; Bs[ldCol + 3][r] = bv.w;
            }
            __syncthreads();
#pragma unroll
            for (int d = 0; d < BD; ++d) {
                float4 a0 = *(const float4*)&As[d][ty * 4];
                float4 a1 = *(const float4*)&As[d][64 + ty * 4];
                float4 b0 = *(const float4*)&Bs[d][ 0 + tx * 4];
                float4 b1 = *(const float4*)&Bs[d][32 + tx * 4];
                float4 b2 = *(const float4*)&Bs[d][64 + tx * 4];
                float4 b3 = *(const float4*)&Bs[d][96 + tx * 4];
                float a[8] = {a0.x,a0.y,a0.z,a0.w,a1.x,a1.y,a1.z,a1.w};
                float b[16] = {b0.x,b0.y,b0.z,b0.w, b1.x,b1.y,b1.z,b1.w,
                               b2.x,b2.y,b2.z,b2.w, b3.x,b3.y,b3.z,b3.w};
#pragma unroll
                for (int i = 0; i < 8; ++i)
#pragma unroll
                    for (int j = 0; j < 16; ++j)
                        acc[i][j] = fmaf(a[i], b[j], acc[i][j]);
            }
            __syncthreads();
        }
#pragma unroll
        for (int j = 0; j < 16; ++j) {
            int code = ct + (j >> 2) * 32 + tx * 4 + (j & 3);
            float c2v = cbs[code];
#pragma unroll
            for (int i = 0; i < 8; ++i) {
                float dist = fmaf(-2.f, acc[i][j], c2v);
                if (dist < bestD[i]) { bestD[i] = dist; bestI[i] = code; }
            }
        }
    }
#pragma unroll
    for (int i = 0; i < 8; ++i) {
        float bd = bestD[i]; int bi = bestI[i];
#pragma unroll
        for (int off = 1; off < 8; off <<= 1) {
            float od = __shfl_xor(bd, off);
            int   oi = __shfl_xor(bi, off);
            if (od < bd || (od == bd && oi < bi)) { bd = od; bi = oi; }
        }
        if (tx == 0) {
            int row = rowBase + ((i < 4) ? ty * 4 + i : 64 + ty * 4 + (i - 4));
            if (nsplit == 1) out[row] = bi;
            else {
                pd[(size_t)row * nsplit + split] = bd;
                pi[(size_t)row * nsplit + split] = bi;
            }
        }
    }
}

__global__ __launch_bounds__(256) void combine_fp32_kernel(
        const float* __restrict__ pd, const int* __restrict__ pi,
        int* __restrict__ out, int N, int S) {
    int r = blockIdx.x * blockDim.x + threadIdx.x;
    if (r >= N) return;
    float bd = pd[(size_t)r * S];
    int bi = pi[(size_t)r * S];
    for (int s = 1; s < S; ++s) {
        float d = pd[(size_t)r * S + s];
        int i = pi[(size_t)r * S + s];
        if (d < bd || (d == bd && i < bi)) { bd = d; bi = i; }
    }
    out[r] = bi;
}

// =========================== launcher ===========================
extern "C" void kernel_launch(void* const* d_in, const int* in_sizes, int n_in,
                              void* d_out, int out_size, void* d_ws, size_t ws_size,
                              hipStream_t stream) {
    const float* X  = (const float*)d_in[0];
    const float* CB = (const float*)d_in[1];
    const int N = in_sizes[0] / D_DIM;
    const int K = in_sizes[1] / D_DIM;
    int* out = (int*)d_out;

    size_t o = 0;
    auto take = [&](size_t bytes) { size_t r = o; o += (bytes + 255) & ~(size_t)255; return r; };
    size_t oCbs = take((size_t)K * 4);
    size_t oXh  = take((size_t)N * D_DIM * 2);
    size_t oCh  = take((size_t)K * D_DIM * 2);
    size_t oPd1 = take((size_t)N * KSPLIT * 4);
    size_t oPi1 = take((size_t)N * KSPLIT * 4);
    size_t oPd2 = take((size_t)N * KSPLIT * 4);
    size_t oPi2 = take((size_t)N * KSPLIT * 4);
    size_t oPd3 = take((size_t)N * KSPLIT * 4);
    size_t oFlg = take((size_t)N * 4);
    size_t oCnt = take(256);
    size_t oScD = take((size_t)N * 32 * 4);
    size_t oScI = take((size_t)N * 32 * 4);
    const size_t need = o;

    char* ws = (char*)d_ws;
    float* cbs = (float*)(ws + oCbs);

    if (ws_size >= need && (N % 256) == 0 && (K % (KSPLIT * 256)) == 0 &&
        (K / KSPLIT) <= 1024 && (K % 32) == 0) {
        _Float16* Xh = (_Float16*)(ws + oXh);
        _Float16* Ch = (_Float16*)(ws + oCh);
        float* pd1 = (float*)(ws + oPd1);
        int*   pi1 = (int*)(ws + oPi1);
        float* pd2 = (float*)(ws + oPd2);
        int*   pi2 = (int*)(ws + oPi2);
        float* pd3 = (float*)(ws + oPd3);
        int* flags = (int*)(ws + oFlg);
        int* cnt   = (int*)(ws + oCnt);
        float* scrD = (float*)(ws + oScD);
        int*   scrI = (int*)(ws + oScI);

        const int cbBlocks = K / 4;
        const int xBlocks  = 2048;
        prep_kernel<<<cbBlocks + xBlocks, 256, 0, stream>>>(
            X, CB, Xh, Ch, cbs, cnt, N * D_DIM / 4, K, cbBlocks, xBlocks);

        vq_mfma_kernel<<<(N / 256) * KSPLIT, 512, 0, stream>>>(
            Xh, Ch, cbs, pd1, pi1, pd2, pi2, pd3, N, K);

        combine_kernel<<<N / 256, 256, 0, stream>>>(
            X, CB, cbs, pd1, pi1, pd2, pi2, pd3, out, flags, cnt, N, KSPLIT);

        rare_scan_kernel<<<1024, 256, 0, stream>>>(
            X, CB, cbs, flags, cnt, scrD, scrI, K);

        rare_write_kernel<<<32, 256, 0, stream>>>(flags, cnt, scrD, scrI, out);
    } else {
        size_t base = ((size_t)K * 4 + 255) & ~(size_t)255;
        int nsplit = 4;
        while (nsplit > 1 &&
               (ws_size < base + (size_t)N * nsplit * 8 || (K % (nsplit * BN)) != 0))
            nsplit >>= 1;
        float* pd = (float*)(ws + base);
        int*   pi = (int*)(ws + base + (size_t)N * nsplit * 4);
        cbsqr_kernel<<<(K + 3) / 4, 256, 0, stream>>>(CB, cbs, K);
        dim3 grid(N / BM, nsplit);
        vq_fp32_kernel<<<grid, 128, 0, stream>>>(X, CB, cbs, pd, pi, out, N, K, nsplit);
        if (nsplit > 1)
            combine_fp32_kernel<<<(N + 255) / 256, 256, 0, stream>>>(pd, pi, out, N, nsplit);
    }
}